// Round 1
// 360.955 us; speedup vs baseline: 1.0089x; 1.0089x over previous
//
#include <hip/hip_runtime.h>
#include <math.h>

#define B 64
#define K 5
#define D 1024
#define H 32
#define W 32
#define N (H * W)
#define BLKS_PER_B (N / 16)  // 64 sims blocks per batch image

typedef unsigned long long u64;
typedef unsigned int u32;

__device__ __forceinline__ float dot4(float4 a, float4 b) {
    return a.x * b.x + a.y * b.y + a.z * b.z + a.w * b.w;
}

// One WAVE per 4 patch rows; block = 4 waves = 16 rows; grid = B*N/16.
// Uses RAW cue (1/||cue|| is a positive per-(b,k) constant -> argmax-invariant).
// 24 accumulators/lane (4 rows x (||p||^2 + 5 dots)); packed exchange
// reduction (masks 1,2,4 halve value count, then full butterfly on 3) =
// 30 DS ops per 4 rows. Argmax fused: candidates packed as
// (monotone_bits(sim) << 32) | (1023 - n) so u64 max == (max sim, min n),
// matching jnp.argmax first-index tie-break.
// NO atomics: each block stores its per-k best to cands[(b*K+k)*64 + jblk];
// every slot is written exactly once, so no memset/init pass is needed.
__global__ __launch_bounds__(256) void sims_argmax(const float* __restrict__ patches,
                                                   const float* __restrict__ cue,
                                                   u64* __restrict__ cands) {
    const int wave = threadIdx.x >> 6;
    const int lane = threadIdx.x & 63;
    const int bn0 = blockIdx.x * 16 + wave * 4;  // 16 | N so b is block-uniform
    const int b = bn0 >> 10;
    const int n0 = bn0 & (N - 1);

    const float4* prow = (const float4*)(patches + (size_t)bn0 * D);
    const float4* crow = (const float4*)(cue + (size_t)b * K * D);

    float acc[24];
#pragma unroll
    for (int v = 0; v < 24; ++v) acc[v] = 0.f;

#pragma unroll
    for (int j = 0; j < 4; ++j) {
        const int idx = j * 64 + lane;  // float4 index within a 256-float4 row
        float4 p[4];
#pragma unroll
        for (int r = 0; r < 4; ++r) p[r] = prow[r * 256 + idx];
#pragma unroll
        for (int r = 0; r < 4; ++r) acc[r * 6] += dot4(p[r], p[r]);
#pragma unroll
        for (int k = 0; k < K; ++k) {
            float4 c = crow[k * 256 + idx];
#pragma unroll
            for (int r = 0; r < 4; ++r) acc[r * 6 + 1 + k] += dot4(p[r], c);
        }
    }

    // --- packed exchange reduction: 24 -> 12 -> 6 -> 3 values/lane ---
#pragma unroll
    for (int i = 0; i < 12; ++i) {
        float t = (lane & 1) ? acc[i] : acc[i + 12];
        float r = __shfl_xor(t, 1, 64);
        acc[i] = ((lane & 1) ? acc[i + 12] : acc[i]) + r;
    }
#pragma unroll
    for (int i = 0; i < 6; ++i) {
        float t = (lane & 2) ? acc[i] : acc[i + 6];
        float r = __shfl_xor(t, 2, 64);
        acc[i] = ((lane & 2) ? acc[i + 6] : acc[i]) + r;
    }
#pragma unroll
    for (int i = 0; i < 3; ++i) {
        float t = (lane & 4) ? acc[i] : acc[i + 3];
        float r = __shfl_xor(t, 4, 64);
        acc[i] = ((lane & 4) ? acc[i + 3] : acc[i]) + r;
    }
#pragma unroll
    for (int m = 8; m <= 32; m <<= 1) {
#pragma unroll
        for (int i = 0; i < 3; ++i) acc[i] += __shfl_xor(acc[i], m, 64);
    }

    __shared__ float slab[4][24];
    __shared__ u64 cand[4][20];
    if (lane < 8) {
        const int base = 12 * (lane & 1) + 6 * ((lane >> 1) & 1) + 3 * ((lane >> 2) & 1);
        slab[wave][base + 0] = acc[0];
        slab[wave][base + 1] = acc[1];
        slab[wave][base + 2] = acc[2];
    }
    __syncthreads();
    if (lane < 4 * K) {
        const int r = lane / K, k = lane % K;
        const float inv = 1.0f / fmaxf(sqrtf(slab[wave][r * 6]), 1e-12f);
        const float s = slab[wave][r * 6 + 1 + k] * inv;
        const u32 bits = __float_as_uint(s);
        const u32 u = bits ^ ((bits & 0x80000000u) ? 0xFFFFFFFFu : 0x80000000u);
        const int n = n0 + r;
        cand[wave][lane] = ((u64)u << 32) | (u32)(N - 1 - n);
    }
    __syncthreads();
    if (threadIdx.x < K) {
        const int k = threadIdx.x;
        u64 best = 0;
#pragma unroll
        for (int w2 = 0; w2 < 4; ++w2)
#pragma unroll
            for (int r = 0; r < 4; ++r) {
                const u64 c = cand[w2][r * K + k];
                if (c > best) best = c;
            }
        const int jblk = blockIdx.x & (BLKS_PER_B - 1);
        cands[((size_t)b * K + k) * BLKS_PER_B + jblk] = best;
    }
}

// One block per (b, k): wave 0 reduces the 64 per-block candidates
// (coalesced 512 B read + 6-step u64 shfl-max butterfly), then all 4 waves
// gather the 3x3 zero-padded neighborhood mean of raw patches.
__global__ __launch_bounds__(256) void gather_kernel(const u64* __restrict__ cands,
                                                     const float* __restrict__ patches,
                                                     float* __restrict__ out) {
    const int row = blockIdx.x;  // b*K + k
    const int b = row / K;
    const int tid = threadIdx.x;

    __shared__ u64 sbest;
    if (tid < 64) {
        u64 c = cands[(size_t)row * BLKS_PER_B + tid];
#pragma unroll
        for (int m = 1; m <= 32; m <<= 1) {
            const u64 o = __shfl_xor(c, m, 64);
            if (o > c) c = o;
        }
        if (tid == 0) sbest = c;
    }
    __syncthreads();

    const u64 c = sbest;
    const int idx = (N - 1) - (int)(c & 0xFFFFFFFFull);
    const int y0 = idx >> 5;   // idx / W
    const int x0 = idx & 31;   // idx % W

    float4 acc = make_float4(0.f, 0.f, 0.f, 0.f);
#pragma unroll
    for (int dy = -1; dy <= 1; ++dy) {
        const int yy = y0 + dy;
        if (yy < 0 || yy >= H) continue;
#pragma unroll
        for (int dx = -1; dx <= 1; ++dx) {
            const int xx = x0 + dx;
            if (xx < 0 || xx >= W) continue;
            const float4* nrow =
                (const float4*)(patches + (((size_t)b * H + yy) * W + xx) * D);
            float4 p = nrow[tid];
            acc.x += p.x; acc.y += p.y; acc.z += p.z; acc.w += p.w;
        }
    }
    const float inv9 = 1.0f / 9.0f;
    float4 o = make_float4(acc.x * inv9, acc.y * inv9, acc.z * inv9, acc.w * inv9);
    ((float4*)(out + (size_t)row * D))[tid] = o;
}

extern "C" void kernel_launch(void* const* d_in, const int* in_sizes, int n_in,
                              void* d_out, int out_size, void* d_ws, size_t ws_size,
                              hipStream_t stream) {
    const float* cue = (const float*)d_in[0];
    const float* patches = (const float*)d_in[1];
    float* out = (float*)d_out;

    u64* cands = (u64*)d_ws;  // B*K*64 u64 per-block candidates (160 KiB)

    sims_argmax<<<(B * N) / 16, 256, 0, stream>>>(patches, cue, cands);
    gather_kernel<<<B * K, 256, 0, stream>>>(cands, patches, out);
}